// Round 5
// baseline (123.759 us; speedup 1.0000x reference)
//
#include <hip/hip_runtime.h>

#define THRESH 0.95f
#define MAXL 64
#define BPB 16      // batches per scan block (lanes 0..15)
#define STR 17      // LDS stride in floats: odd -> 16 lanes hit 16 distinct banks
#define TPAD 2008   // T(<=2000) + 8 prefetch overrun

// Kernel A v5: lane-parallel scan. One block handles BPB batches; 256 threads
// stage alphas rows into LDS transposed (sa[t*STR + lane], conflict-free),
// then lanes 0..BPB-1 each run the bit-exact serial integrate-and-fire chain
// for their batch:  x = integ + a; fire = x > 0.95; integ = fire ? x-1 : x
// (sub precomputed off-chain; ~12 cyc dependent path/step, SIMD across 16
// batches). Fire record = one predicated 8B store {dc bits, t}; rem is
// recomputed bit-exactly in the gather as alphas[tp] - dc.
// LDS reads are prefetched 8-16 steps ahead into two named register banks.
__global__ __launch_bounds__(256) void cif_scan(
    const float* __restrict__ alphas, int T, int B,
    int* __restrict__ nf, uint2* __restrict__ recs) {
    __shared__ float sa[STR * TPAD];
    int b0 = blockIdx.x * BPB;
    int tid = threadIdx.x;
    int nb = B - b0; if (nb > BPB) nb = BPB;

    // ---- stage: [nb][T] row-major global -> sa[t*STR + bl] (transposed)
    const float* gbase = alphas + (size_t)b0 * T;
    int ROW4 = T >> 2;
    if ((((uintptr_t)gbase) & 15) == 0 && (T & 3) == 0) {
        const float4* g4 = (const float4*)gbase;   // block rows are contiguous
        int TOT4 = nb * ROW4;
        for (int base = 0; base < TOT4; base += 256 * 8) {
            float4 v[8]; int ii[8];
            #pragma unroll
            for (int k = 0; k < 8; ++k) {          // 8 loads in flight
                ii[k] = base + k * 256 + tid;
                if (ii[k] < TOT4) v[k] = g4[ii[k]];
            }
            #pragma unroll
            for (int k = 0; k < 8; ++k) {
                if (ii[k] < TOT4) {
                    int bl = ii[k] / ROW4, j = ii[k] - bl * ROW4, t = j << 2;
                    sa[(t    ) * STR + bl] = v[k].x;
                    sa[(t + 1) * STR + bl] = v[k].y;
                    sa[(t + 2) * STR + bl] = v[k].z;
                    sa[(t + 3) * STR + bl] = v[k].w;
                }
            }
        }
    } else {
        for (int idx = tid; idx < nb * T; idx += 256) {
            int bl = idx / T, t = idx - bl * T;
            sa[t * STR + bl] = gbase[(size_t)bl * T + t];
        }
    }
    __syncthreads();

    if (tid >= nb) return;
    int bl = tid;
    float integ = 0.0f;
    int n = 0;
    uint2* rec = recs + (size_t)(b0 + bl) * MAXL;

#define ONESTEP(AV, TT)                                                      \
    {                                                                        \
        float pre = integ;                                                   \
        float x = pre + (AV);                                                \
        float y = x - 1.0f;                                                  \
        bool f = x > THRESH;                                                 \
        integ = f ? y : x;                                                   \
        if (f) {                                                             \
            if (n < MAXL) {                                                  \
                float dc = 1.0f - pre;                                       \
                rec[n] = make_uint2(__float_as_uint(dc), (unsigned)(TT));    \
            }                                                                \
            ++n;                                                             \
        }                                                                    \
    }

    int Tm = T & ~15;           // 16-step two-phase main loop (no reg rotation)
    if (Tm >= 16) {
        float p0, p1, p2, p3, p4, p5, p6, p7;
        float q0, q1, q2, q3, q4, q5, q6, q7;
        p0 = sa[0 * STR + bl]; p1 = sa[1 * STR + bl];
        p2 = sa[2 * STR + bl]; p3 = sa[3 * STR + bl];
        p4 = sa[4 * STR + bl]; p5 = sa[5 * STR + bl];
        p6 = sa[6 * STR + bl]; p7 = sa[7 * STR + bl];
        for (int t0 = 0; t0 < Tm; t0 += 16) {
            // phase A: consume p (t0..t0+7), prefetch q <- t0+8..t0+15
            q0 = sa[(t0 +  8) * STR + bl]; q1 = sa[(t0 +  9) * STR + bl];
            q2 = sa[(t0 + 10) * STR + bl]; q3 = sa[(t0 + 11) * STR + bl];
            q4 = sa[(t0 + 12) * STR + bl]; q5 = sa[(t0 + 13) * STR + bl];
            q6 = sa[(t0 + 14) * STR + bl]; q7 = sa[(t0 + 15) * STR + bl];
            ONESTEP(p0, t0 + 0) ONESTEP(p1, t0 + 1)
            ONESTEP(p2, t0 + 2) ONESTEP(p3, t0 + 3)
            ONESTEP(p4, t0 + 4) ONESTEP(p5, t0 + 5)
            ONESTEP(p6, t0 + 6) ONESTEP(p7, t0 + 7)
            // phase B: consume q, prefetch p <- t0+16..t0+23 (pad covers T+8)
            p0 = sa[(t0 + 16) * STR + bl]; p1 = sa[(t0 + 17) * STR + bl];
            p2 = sa[(t0 + 18) * STR + bl]; p3 = sa[(t0 + 19) * STR + bl];
            p4 = sa[(t0 + 20) * STR + bl]; p5 = sa[(t0 + 21) * STR + bl];
            p6 = sa[(t0 + 22) * STR + bl]; p7 = sa[(t0 + 23) * STR + bl];
            ONESTEP(q0, t0 +  8) ONESTEP(q1, t0 +  9)
            ONESTEP(q2, t0 + 10) ONESTEP(q3, t0 + 11)
            ONESTEP(q4, t0 + 12) ONESTEP(q5, t0 + 13)
            ONESTEP(q6, t0 + 14) ONESTEP(q7, t0 + 15)
        }
    }
    for (int t = Tm; t < T; ++t) {      // generic tail
        float a = sa[t * STR + bl];
        ONESTEP(a, t)
    }
#undef ONESTEP
    nf[b0 + bl] = (n < MAXL) ? n : MAXL;
}

// Kernel B (at HBM roofline): one block per (batch, label), float4 over H.
// out[b,k,:] = rem[k-1]*h[tp] + sum_{t in (tp,tf)} a_t*h[t] + cur*h[tf],
// ascending t (matches reference rounding; absmax was 0.0). rem[k-1] is
// recomputed as arow[tp] - dc[k-1] — bit-identical to the scan's a - dc.
// Labels k >= fire count write zeros (d_out is poisoned by the harness).
__global__ __launch_bounds__(128) void cif_gather(
    const float* __restrict__ hidden, const float* __restrict__ alphas,
    int T, int H,
    const int* __restrict__ nf, const uint2* __restrict__ recs,
    float* __restrict__ out) {
    int b = blockIdx.x >> 6;
    int k = blockIdx.x & (MAXL - 1);

    int valid = (k < nf[b]);
    int tf = 0, t0 = 0, tp = 0;
    float rw = 0.0f, cw = 0.0f;
    const float* arow = alphas + (size_t)b * T;
    if (valid) {
        uint2 r = recs[(size_t)b * MAXL + k];
        cw = __uint_as_float(r.x);
        tf = (int)r.y;
        if (k > 0) {
            uint2 rp = recs[(size_t)b * MAXL + k - 1];
            tp = (int)rp.y;
            rw = arow[tp] - __uint_as_float(rp.x);   // rem = a - dc, bit-exact
            t0 = tp + 1;
        }
    }

    if ((H & 3) == 0) {
        int W = H >> 2;
        const float4* hb4 = (const float4*)(hidden + (size_t)b * T * H);
        float4* out4 = (float4*)(out + (size_t)blockIdx.x * H);
        for (int h4 = threadIdx.x; h4 < W; h4 += blockDim.x) {
            float4 acc = make_float4(0.f, 0.f, 0.f, 0.f);
            if (valid) {
                if (k > 0) {
                    float4 m = hb4[(size_t)tp * W + h4];
                    acc.x = rw * m.x; acc.y = rw * m.y;
                    acc.z = rw * m.z; acc.w = rw * m.w;
                }
                for (int t = t0; t < tf; ++t) {
                    float4 m = hb4[(size_t)t * W + h4];
                    float a = arow[t];
                    acc.x += a * m.x; acc.y += a * m.y;
                    acc.z += a * m.z; acc.w += a * m.w;
                }
                float4 m = hb4[(size_t)tf * W + h4];
                acc.x += cw * m.x; acc.y += cw * m.y;
                acc.z += cw * m.z; acc.w += cw * m.w;
            }
            out4[h4] = acc;
        }
    } else {
        const float* hb = hidden + (size_t)b * T * H;
        size_t obase = (size_t)blockIdx.x * H;
        for (int h = threadIdx.x; h < H; h += blockDim.x) {
            float acc = 0.0f;
            if (valid) {
                if (k > 0) acc = rw * hb[(size_t)tp * H + h];
                for (int t = t0; t < tf; ++t)
                    acc += arow[t] * hb[(size_t)t * H + h];
                acc += cw * hb[(size_t)tf * H + h];
            }
            out[obase + h] = acc;
        }
    }
}

extern "C" void kernel_launch(void* const* d_in, const int* in_sizes, int n_in,
                              void* d_out, int out_size, void* d_ws, size_t ws_size,
                              hipStream_t stream) {
    const float* hidden = (const float*)d_in[0];
    const float* alphas = (const float*)d_in[1];
    float* out = (float*)d_out;

    long BT  = in_sizes[1];          // B*T
    long BTH = in_sizes[0];          // B*T*H
    int H = (int)(BTH / BT);         // 512
    int B = (int)((long)out_size / ((long)MAXL * H)); // 32
    int T = (int)(BT / B);           // 2000  (<= TPAD-8 by problem shape)

    char* ws = (char*)d_ws;
    int*   nf   = (int*)ws;                          // B ints
    uint2* recs = (uint2*)(ws + 256);                // B*MAXL uint2

    int nblk = (B + BPB - 1) / BPB;
    cif_scan<<<nblk, 256, 0, stream>>>(alphas, T, B, nf, recs);
    cif_gather<<<B * MAXL, 128, 0, stream>>>(hidden, alphas, T, H, nf, recs, out);
}

// Round 6
// 107.117 us; speedup vs baseline: 1.1554x; 1.1554x over previous
//
#include <hip/hip_runtime.h>

#define THRESH 0.95f
#define MAXL 64
#define RSTR 65   // record slots per batch: 64 labels + 1 dump slot

// Kernel A v6: branchless lane-parallel scan. One wave; lane = batch.
// Bit-exact chain per step:  x = integ + a; f = x > 0.95; integ = f ? x-1 : x
// (sub is Sterbenz-exact; identical op order to the reference scan).
// Fire recording WITHOUT a branch: every step stores {pre, t} to
// rec[min(n,64)] and n increments only on fire -> the last write to slot n
// before n advances is the fire step itself, so rec[0..63] ends up holding
// exactly the fire records (slot 64 = dump, like the reference's MAXL+1).
// dc and rem are recomputed bit-exactly in the gather (dc = 1-pre, rem = a-dc).
// Alphas are read straight from global (256 KB, L2-resident) as float4 with
// 4 named prefetch buffers = 16-step (~300 cyc) lookahead; no LDS, no sync.
__global__ __launch_bounds__(64) void cif_scan(
    const float* __restrict__ alphas, int T, int B,
    int* __restrict__ nf, uint2* __restrict__ recs) {
    int lane = threadIdx.x;
    int b = blockIdx.x * 64 + lane;
    if (b >= B) return;
    const float* arow = alphas + (size_t)b * T;
    uint2* rec = recs + (size_t)b * RSTR;

    float integ = 0.0f;
    unsigned n = 0;

#define ONESTEP(AV, TT)                                                      \
    {                                                                        \
        float pre = integ;                                                   \
        float x = pre + (AV);                                                \
        float y = x - 1.0f;                                                  \
        bool f = x > THRESH;                                                 \
        integ = f ? y : x;                                                   \
        unsigned idx = (n < 64u) ? n : 64u;                                  \
        rec[idx] = make_uint2(__float_as_uint(pre), (unsigned)(TT));         \
        n += f ? 1u : 0u;                                                    \
    }

#define STEP4(CF, TB)                                                        \
    {                                                                        \
        ONESTEP((CF).x, (TB))                                                \
        ONESTEP((CF).y, (TB) + 1)                                            \
        ONESTEP((CF).z, (TB) + 2)                                            \
        ONESTEP((CF).w, (TB) + 3)                                            \
    }

    bool fast = ((((uintptr_t)arow) & 15) == 0) && ((T & 3) == 0) && (T >= 32);
    if (fast) {
        const float4* g4 = (const float4*)arow;
        int nwin = T >> 2;
        float4 f0 = g4[0], f1 = g4[1], f2 = g4[2], f3 = g4[3];
        int w = 0;
        for (; w + 8 <= nwin; w += 4) {      // consume w..w+3, prefetch w+4..w+7
            float4 c;
            c = f0; f0 = g4[w + 4]; STEP4(c, (w    ) << 2);
            c = f1; f1 = g4[w + 5]; STEP4(c, (w + 1) << 2);
            c = f2; f2 = g4[w + 6]; STEP4(c, (w + 2) << 2);
            c = f3; f3 = g4[w + 7]; STEP4(c, (w + 3) << 2);
        }
        // 4 buffered windows left (nwin - w in [4,7]; f0..f3 hold w..w+3)
        STEP4(f0, (w) << 2) STEP4(f1, (w + 1) << 2)
        STEP4(f2, (w + 2) << 2) STEP4(f3, (w + 3) << 2)
        for (int t = (w + 4) << 2; t < T; ++t) {   // up to 12 leftover steps
            float a = arow[t];
            ONESTEP(a, t)
        }
    } else {
        for (int t = 0; t < T; ++t) {
            float a = arow[t];
            ONESTEP(a, t)
        }
    }
#undef STEP4
#undef ONESTEP
    nf[b] = (n < 64u) ? (int)n : 64;
}

// Kernel B (at HBM roofline, unchanged math): one block per (batch, label),
// float4 over H, ascending-t accumulation (absmax 0.0 in rounds 1-5).
//   out[b,k,:] = rem[k-1]*h[tp] + sum_{t in (tp,tf)} a_t*h[t] + dc_k*h[tf]
// with dc = 1 - pre (bit-exact: same op as reference's dist_completion) and
// rem = a[tp] - dc_prev (bit-exact: same as reference's a - cur).
// Labels k >= fire count write zeros (d_out is poisoned by the harness).
__global__ __launch_bounds__(128) void cif_gather(
    const float* __restrict__ hidden, const float* __restrict__ alphas,
    int T, int H,
    const int* __restrict__ nf, const uint2* __restrict__ recs,
    float* __restrict__ out) {
    int b = blockIdx.x >> 6;
    int k = blockIdx.x & (MAXL - 1);

    int valid = (k < nf[b]);
    int tf = 0, t0 = 0, tp = 0;
    float rw = 0.0f, cw = 0.0f;
    const float* arow = alphas + (size_t)b * T;
    if (valid) {
        uint2 r = recs[(size_t)b * RSTR + k];
        cw = 1.0f - __uint_as_float(r.x);            // dc = 1 - pre, bit-exact
        tf = (int)r.y;
        if (k > 0) {
            uint2 rp = recs[(size_t)b * RSTR + k - 1];
            tp = (int)rp.y;
            float dcp = 1.0f - __uint_as_float(rp.x);
            rw = arow[tp] - dcp;                     // rem = a - dc, bit-exact
            t0 = tp + 1;
        }
    }

    if ((H & 3) == 0) {
        int W = H >> 2;
        const float4* hb4 = (const float4*)(hidden + (size_t)b * T * H);
        float4* out4 = (float4*)(out + (size_t)blockIdx.x * H);
        for (int h4 = threadIdx.x; h4 < W; h4 += blockDim.x) {
            float4 acc = make_float4(0.f, 0.f, 0.f, 0.f);
            if (valid) {
                if (k > 0) {
                    float4 m = hb4[(size_t)tp * W + h4];
                    acc.x = rw * m.x; acc.y = rw * m.y;
                    acc.z = rw * m.z; acc.w = rw * m.w;
                }
                for (int t = t0; t < tf; ++t) {
                    float4 m = hb4[(size_t)t * W + h4];
                    float a = arow[t];
                    acc.x += a * m.x; acc.y += a * m.y;
                    acc.z += a * m.z; acc.w += a * m.w;
                }
                float4 m = hb4[(size_t)tf * W + h4];
                acc.x += cw * m.x; acc.y += cw * m.y;
                acc.z += cw * m.z; acc.w += cw * m.w;
            }
            out4[h4] = acc;
        }
    } else {
        const float* hb = hidden + (size_t)b * T * H;
        size_t obase = (size_t)blockIdx.x * H;
        for (int h = threadIdx.x; h < H; h += blockDim.x) {
            float acc = 0.0f;
            if (valid) {
                if (k > 0) acc = rw * hb[(size_t)tp * H + h];
                for (int t = t0; t < tf; ++t)
                    acc += arow[t] * hb[(size_t)t * H + h];
                acc += cw * hb[(size_t)tf * H + h];
            }
            out[obase + h] = acc;
        }
    }
}

extern "C" void kernel_launch(void* const* d_in, const int* in_sizes, int n_in,
                              void* d_out, int out_size, void* d_ws, size_t ws_size,
                              hipStream_t stream) {
    const float* hidden = (const float*)d_in[0];
    const float* alphas = (const float*)d_in[1];
    float* out = (float*)d_out;

    long BT  = in_sizes[1];          // B*T
    long BTH = in_sizes[0];          // B*T*H
    int H = (int)(BTH / BT);         // 512
    int B = (int)((long)out_size / ((long)MAXL * H)); // 32
    int T = (int)(BT / B);           // 2000

    char* ws = (char*)d_ws;
    int*   nf   = (int*)ws;                          // B ints
    uint2* recs = (uint2*)(ws + 256);                // B*RSTR uint2

    int nblk = (B + 63) / 64;
    cif_scan<<<nblk, 64, 0, stream>>>(alphas, T, B, nf, recs);
    cif_gather<<<B * MAXL, 128, 0, stream>>>(hidden, alphas, T, H, nf, recs, out);
}